// Round 1
// 204.146 us; speedup vs baseline: 1.1820x; 1.1820x over previous
//
#include <hip/hip_runtime.h>
#include <hip/hip_bf16.h>
#include <math.h>

#define NWRD 2000
#define BB 64
#define CS 128
#define VV 256

typedef __attribute__((ext_vector_type(8)))  short short8;   // 8 bf16 (4 VGPRs)
typedef __attribute__((ext_vector_type(16))) float f32x16;   // MFMA 32x32 acc

// workspace layout (float offsets) — geometry kept; W2T/H0B slots now unused
#define WS_FC2WT 0                         // 256*256 bf16
#define WS_WCODE (WS_FC2WT + 32768)        // 64*6000 f32  ([b][n*3+c])
#define WS_VSB   (WS_WCODE + 384000)       // 256*32 bf16
#define WS_W2T   (WS_VSB + 4096)           // (unused)
#define WS_VCB   (WS_W2T + 1536000)        // 64*128*256 bf16
#define WS_FCEWT (WS_VCB + 1048576)        // 32*256 bf16
#define WS_H0B   (WS_FCEWT + 4096)         // (unused)
#define WS_FCAWB (WS_H0B + 16384)          // 32*256 bf16 (col0=fca_w, rest 0)

__device__ __forceinline__ unsigned short f2bf(float x) {
    unsigned int u = __float_as_uint(x);
    u += 0x7fffu + ((u >> 16) & 1u);       // round-to-nearest-even
    return (unsigned short)(u >> 16);
}
// hardware packed f32->bf16 (RNE), 1 instr per 2 values (no builtin on gfx950)
__device__ __forceinline__ unsigned int pkbf(float lo, float hi) {
    unsigned int r;
    asm("v_cvt_pk_bf16_f32 %0, %1, %2" : "=v"(r) : "v"(lo), "v"(hi));
    return r;
}

// ================ KPREP: prep jobs + fused wcode GEMM in ONE launch ================
// blocks [0,94): wcode GEMM (self-contained: recomputes h0, LDS-transposes w2 slice)
// [94,1118): vcb convert | [1118,1150): vsb | [1150,1166): fc2wT | 1166: fcewT+fcawB
#define PR_K2  94
#define PR_VCB (PR_K2 + 1024)
#define PR_VSB (PR_VCB + 32)
#define PR_FC2 (PR_VSB + 16)
#define PREP_N (PR_FC2 + 1)
__global__ __launch_bounds__(256) void kprep(
        const float* __restrict__ vc, unsigned short* __restrict__ vcb,
        const float* __restrict__ w2,
        const float* __restrict__ v, const float* __restrict__ w1,
        const float* __restrict__ b1, const float* __restrict__ b2,
        float* __restrict__ wcode,
        const float* __restrict__ vse_w1, const float* __restrict__ vse_b1,
        const float* __restrict__ vse_w2, const float* __restrict__ vse_b2,
        unsigned short* __restrict__ vsb,
        const float* __restrict__ fc2_w, unsigned short* __restrict__ fc2wT,
        const float* __restrict__ fce_w, unsigned short* __restrict__ fcewT,
        const float* __restrict__ fca_w, unsigned short* __restrict__ fcawB) {
    __shared__ __align__(16) unsigned short smem[9216];   // unioned scratch (18.4 KB)
    int bid = blockIdx.x, t = threadIdx.x;
    if (bid < PR_K2) {
        // ---- wcode[64 b][64 n cols] = relu(v@w1+b1) @ w2[:,slice] + b2, via MFMA
        // per k-panel of 64: ha = h0 panel bf16 [64 m][72], wb = w2^T panel [64 n][72]
        unsigned short* ha = smem;            // [64][72]  (stride 144B, 16B-aligned)
        unsigned short* wb = smem + 4608;     // [64][72]
        int n0 = bid * 64;
        int w = t >> 6, lane = t & 63, l31 = lane & 31, h = lane >> 5;
        int mt = w & 1, nt = w >> 1;          // 4 waves: (m-half, n-half)
        int kk = t & 63, mg = t >> 6;
        int colc = n0 + kk; if (colc > 5999) colc = 5999;
        f32x16 acc;
#pragma unroll
        for (int i = 0; i < 16; i++) acc[i] = 0.f;
        for (int p = 0; p < 8; p++) {
            int k0 = p * 64;
            // h0 panel: thread owns column kk, 16 rows (m = b index); w1 reads coalesced
            float w1c[7];
#pragma unroll
            for (int q = 0; q < 7; q++) w1c[q] = w1[q*512 + k0 + kk];
            float bbv = b1[k0 + kk];
#pragma unroll
            for (int mm = 0; mm < 16; mm++) {
                int m = mg*16 + mm;           // wave-uniform m -> scalar v loads
                float s = bbv;
#pragma unroll
                for (int q = 0; q < 7; q++) s = fmaf(v[m*7 + q], w1c[q], s);
                ha[m*72 + kk] = f2bf(fmaxf(s, 0.f));
            }
            // w2 panel transpose: coalesced f32 row reads -> bf16 n-major LDS
#pragma unroll
            for (int i = 0; i < 16; i++)
                wb[kk*72 + mg*16 + i] = f2bf(w2[(size_t)(k0 + mg*16 + i)*6000 + colc]);
            __syncthreads();
#pragma unroll
            for (int ks = 0; ks < 4; ks++) {
                short8 af = *(const short8*)(ha + (mt*32 + l31)*72 + ks*16 + h*8);
                short8 bf = *(const short8*)(wb + (nt*32 + l31)*72 + ks*16 + h*8);
                acc = __builtin_amdgcn_mfma_f32_32x32x16_bf16(af, bf, acc, 0, 0, 0);
            }
            __syncthreads();
        }
        int n = n0 + nt*32 + l31;
        if (n < 6000) {
            float bias = b2[n];
#pragma unroll
            for (int i = 0; i < 16; i++) {
                int row = (i & 3) + 8*(i >> 2) + 4*h;
                wcode[(size_t)(mt*32 + row)*6000 + n] = acc[i] + bias;
            }
        }
    } else if (bid < PR_VCB) {
        // ---- view_cell f32 -> bf16
        int i = ((bid - PR_K2) * 256 + t) * 8;
        float4 f0 = *(const float4*)(vc + i);
        float4 f1 = *(const float4*)(vc + i + 4);
        union { short8 v8; unsigned int u[4]; } o;
        o.u[0] = pkbf(f0.x, f0.y); o.u[1] = pkbf(f0.z, f0.w);
        o.u[2] = pkbf(f1.x, f1.y); o.u[3] = pkbf(f1.z, f1.w);
        *(short8*)(vcb + i) = o.v8;
    } else if (bid < PR_VSB) {
        // ---- vs MLP -> bf16
        float* hs = (float*)smem;   // [8][128]
        int blk = bid - PR_VCB;
        int m = t & 127, half = t >> 7;
#pragma unroll
        for (int q = 0; q < 4; q++) {
            int vloc = half*4 + q;
            int vv = blk*8 + vloc;
            float x = (2.f/15.f)*(float)(vv >> 4) - 1.f;
            float y = (2.f/15.f)*(float)(vv & 15) - 1.f;
            float hh = vse_b1[m] + x*vse_w1[m] + y*vse_w1[128 + m];
            hs[vloc*128 + m] = fmaxf(hh, 0.f);
        }
        __syncthreads();
        int vloc = t >> 5, e = t & 31;
        float s = vse_b2[e];
        for (int mm = 0; mm < 128; mm++) s = fmaf(hs[vloc*128 + mm], vse_w2[mm*32 + e], s);
        vsb[(blk*8 + vloc)*32 + e] = f2bf(s);
    } else if (bid < PR_FC2) {
        // ---- fc2_w -> fc2wT (n-major bf16)
        unsigned short (*tile)[72] = (unsigned short(*)[72])smem;
        int b2t = bid - PR_VSB;
        int k0t = (b2t >> 2) * 64, n0t = (b2t & 3) * 64;
        int nl = t & 63, kb = (t >> 6) * 16;
#pragma unroll
        for (int i = 0; i < 16; i++)
            tile[kb + i][nl] = f2bf(fc2_w[(size_t)(k0t + kb + i)*256 + n0t + nl]);
        __syncthreads();
        int kl = t & 63, nb = (t >> 6) * 16;
#pragma unroll
        for (int i = 0; i < 16; i++)
            fc2wT[(size_t)(n0t + nb + i)*256 + k0t + kl] = tile[kl][nb + i];
    } else {
        // ---- fcewT (32x256 bf16, e-major) + fcawB (col0 = fca_w, rest 0)
        int e = t & 31, kb = (t >> 5) * 32;
        unsigned short tmp[32];
#pragma unroll
        for (int i = 0; i < 32; i++) tmp[i] = f2bf(fce_w[(size_t)(kb + i)*32 + e]);
#pragma unroll
        for (int i = 0; i < 4; i++)
            *(short8*)(fcewT + (size_t)e*256 + kb + i*8) = *(short8*)(tmp + i*8);
#pragma unroll
        for (int i = 0; i < 32; i++)
            fcawB[(size_t)e*256 + kb + i] = (e == 0) ? f2bf(fca_w[kb + i]) : (unsigned short)0;
    }
}

// ================ K45: fused MLP + relation + softmax + einsum ================
// grid (8 nblk, 64 b), 512 threads (8 waves), 4 chunks of 64 words.
// LDS: h1b [64][264] @0 | h2b/routeB [64][264] @33792 | embL [64][40] @67584 |
//      actL[64] @72704 | wcsAll[768] @72960 | redS[8][32] @76032. total 77056 B
#define K45_LDS 77056
__global__ __launch_bounds__(512, 4) void k45(
        const unsigned short* __restrict__ vcb,
        const float* __restrict__ wcode,
        const float* __restrict__ fc1_w, const float* __restrict__ fc1_b,
        const unsigned short* __restrict__ fc2wT, const float* __restrict__ fc2_b,
        const float* __restrict__ fca_b_p,
        const unsigned short* __restrict__ fcawB,
        const unsigned short* __restrict__ fcewT, const float* __restrict__ fce_b,
        const unsigned short* __restrict__ vsb,
        float* __restrict__ out) {
    extern __shared__ char lds[];
    unsigned short* h1b    = (unsigned short*)lds;            // [64][264]
    unsigned short* h2b    = (unsigned short*)(lds + 33792);  // [64][264]
    unsigned short* routeB = h2b;                             // alias (h2 dead by write time)
    unsigned short* embL   = (unsigned short*)(lds + 67584);  // [64][40]
    float* actL   = (float*)(lds + 72704);                    // [64]
    float* wcsAll = (float*)(lds + 72960);                    // [768]
    float* redS   = (float*)(lds + 76032);                    // [8][32]
    int t = threadIdx.x;
    int w = t >> 6, lane = t & 63, l31 = lane & 31, h = lane >> 5;
    int b = blockIdx.y;
    int n0 = blockIdx.x * 256;

    // ---- stage all 4 chunks' wcode once (768 f32)
    {
        const float* wb = wcode + (size_t)b*6000;
        int i0 = n0*3 + t;
        wcsAll[t] = wb[i0 < 6000 ? i0 : 5999];
        if (t < 256) {
            int i1 = n0*3 + 512 + t;
            wcsAll[512 + t] = wb[i1 < 6000 ? i1 : 5999];
        }
    }
    // hoisted invariants
    int jq = (t & 63) * 4;
    float4 wa  = *(const float4*)(fc1_w + jq);
    float4 wb4 = *(const float4*)(fc1_w + 256 + jq);
    float4 wc  = *(const float4*)(fc1_w + 512 + jq);
    float4 bb4 = *(const float4*)(fc1_b + jq);
    int nW = w*32 + l31;                                      // fc2: wave = one n-tile
    float b2v = fc2_b[nW];
    float be = fce_b[l31];
    float fcab = fca_b_p[0];
    int ntR = w & 1, vq = w >> 1;                             // relation tiling
    int ctE = w >> 1, ntE = w & 1;                            // einsum tiling
    size_t arowE = ((size_t)(b*128 + ctE*32 + l31))*256;
    __syncthreads();

    for (int c = 0; c < 4; c++) {
        int w0 = n0 + c*64;
        // ---- fc1 (VALU) -> h1b   (overlaps prev chunk's einsum)
#pragma unroll
        for (int rr = 0; rr < 8; rr++) {
            int r = w*8 + rr;
            const float* wr = wcsAll + (c*64 + r)*3;
            float c0 = wr[0], c1 = wr[1], c2 = wr[2];
            float v0 = fmaxf(fmaf(c2, wc.x, fmaf(c1, wb4.x, fmaf(c0, wa.x, bb4.x))), 0.f);
            float v1 = fmaxf(fmaf(c2, wc.y, fmaf(c1, wb4.y, fmaf(c0, wa.y, bb4.y))), 0.f);
            float v2 = fmaxf(fmaf(c2, wc.z, fmaf(c1, wb4.z, fmaf(c0, wa.z, bb4.z))), 0.f);
            float v3 = fmaxf(fmaf(c2, wc.w, fmaf(c1, wb4.w, fmaf(c0, wa.w, bb4.w))), 0.f);
            uint2 p;
            p.x = pkbf(v0, v1);
            p.y = pkbf(v2, v3);
            *(uint2*)(h1b + r*264 + jq) = p;
        }
        __syncthreads();   // B1: h1b ready; prev einsum's routeB reads done
        // ---- fc2 (MFMA) -> h2b : wave owns one 32-col n-tile, both M-halves
        // (B-fragment loaded ONCE -> halves fc2wT L2 streaming vs mt-duplicated map)
        {
            f32x16 c0, c1;
#pragma unroll
            for (int i = 0; i < 16; i++) { c0[i] = 0.f; c1[i] = 0.f; }
#pragma unroll 4
            for (int ks = 0; ks < 16; ks++) {
                int k0 = ks*16 + h*8;
                short8 bf  = *(const short8*)(fc2wT + (size_t)nW*256 + k0);
                short8 af0 = *(const short8*)(h1b + l31*264 + k0);
                short8 af1 = *(const short8*)(h1b + (32 + l31)*264 + k0);
                c0 = __builtin_amdgcn_mfma_f32_32x32x16_bf16(af0, bf, c0, 0, 0, 0);
                c1 = __builtin_amdgcn_mfma_f32_32x32x16_bf16(af1, bf, c1, 0, 0, 0);
            }
#pragma unroll
            for (int i = 0; i < 16; i++) {
                int row = (i & 3) + 8*(i >> 2) + 4*h;
                unsigned int pk = pkbf(fmaxf(c0[i] + b2v, 0.f), fmaxf(c1[i] + b2v, 0.f));
                h2b[row*264 + nW]        = (unsigned short)pk;
                h2b[(row + 32)*264 + nW] = (unsigned short)(pk >> 16);
            }
        }
        __syncthreads();   // B2
        // ---- fce (waves 0-1) + fca-as-MFMA (waves 2-3) -> embL, actL
        if (w < 2) {
            f32x16 ce;
#pragma unroll
            for (int i = 0; i < 16; i++) ce[i] = 0.f;
#pragma unroll 4
            for (int ks = 0; ks < 16; ks++) {
                int k0 = ks*16 + h*8;
                short8 af = *(const short8*)(h2b + (w*32 + l31)*264 + k0);
                short8 bf = *(const short8*)(fcewT + (size_t)l31*256 + k0);
                ce = __builtin_amdgcn_mfma_f32_32x32x16_bf16(af, bf, ce, 0, 0, 0);
            }
#pragma unroll
            for (int i = 0; i < 16; i += 2) {
                int row = (i & 3) + 8*(i >> 2) + 4*h;
                unsigned int pk = pkbf(ce[i] + be, ce[i+1] + be);
                embL[(w*32 + row)*40 + l31]     = (unsigned short)pk;
                embL[(w*32 + row + 1)*40 + l31] = (unsigned short)(pk >> 16);
            }
        } else if (w < 4) {
            int m = w - 2;
            f32x16 ca;
#pragma unroll
            for (int i = 0; i < 16; i++) ca[i] = 0.f;
#pragma unroll 4
            for (int ks = 0; ks < 16; ks++) {
                int k0 = ks*16 + h*8;
                short8 af = *(const short8*)(h2b + (m*32 + l31)*264 + k0);
                short8 bf = *(const short8*)(fcawB + (size_t)l31*256 + k0);
                ca = __builtin_amdgcn_mfma_f32_32x32x16_bf16(af, bf, ca, 0, 0, 0);
            }
            if (l31 == 0) {
#pragma unroll
                for (int i = 0; i < 16; i++) {
                    int row = (i & 3) + 8*(i >> 2) + 4*h;
                    actL[m*32 + row] = 1.f / (1.f + __expf(-(ca[i] + fcab)));
                }
            }
        }
        __syncthreads();   // B3: embL, actL ready
        // ---- relation (MFMA): wave = (n-tile ntR, v-quarter vq)
        int nloc = ntR*32 + l31;
        f32x16 ra[2];
#pragma unroll
        for (int mt = 0; mt < 2; mt++)
#pragma unroll
            for (int i = 0; i < 16; i++) ra[mt][i] = 0.f;
#pragma unroll
        for (int s = 0; s < 2; s++) {
            short8 bfrag = *(const short8*)(embL + nloc*40 + s*16 + h*8);
#pragma unroll
            for (int mt = 0; mt < 2; mt++) {
                int vrow = (vq*2 + mt)*32 + l31;
                short8 afrag = *(const short8*)(vsb + vrow*32 + s*16 + h*8);
                ra[mt] = __builtin_amdgcn_mfma_f32_32x32x16_bf16(afrag, bfrag, ra[mt], 0, 0, 0);
            }
        }
        // ---- softmax over v=256 (no max-sub: logits are tiny; exact same math)
        float sm = 0.f;
#pragma unroll
        for (int mt = 0; mt < 2; mt++)
#pragma unroll
            for (int i = 0; i < 16; i++) {
                float e = __expf(ra[mt][i]);
                ra[mt][i] = e;
                sm += e;
            }
        sm += __shfl_xor(sm, 32);
        if (lane < 32) redS[w*32 + l31] = sm;
        __syncthreads();   // B4
        sm = 0.f;
#pragma unroll
        for (int q = 0; q < 4; q++) sm += redS[(q*2 + ntR)*32 + l31];
        float scale = actL[nloc] / sm;
        // ---- routeB[n][v] bf16 (aliases h2b - dead after fce/fca)
#pragma unroll
        for (int mt = 0; mt < 2; mt++) {
#pragma unroll
            for (int rp = 0; rp < 4; rp++) {
                int vb = (vq*2 + mt)*32 + rp*8 + h*4;
                unsigned int p0 = pkbf(ra[mt][rp*4+0]*scale, ra[mt][rp*4+1]*scale);
                unsigned int p1 = pkbf(ra[mt][rp*4+2]*scale, ra[mt][rp*4+3]*scale);
                *(uint2*)(routeB + nloc*264 + vb) = make_uint2(p0, p1);
            }
        }
        __syncthreads();   // B5: routeB ready
        // ---- einsum (MFMA): out[c 128][n 64] = vcb[b] @ routeB^T
        {
            f32x16 cc;
#pragma unroll
            for (int i = 0; i < 16; i++) cc[i] = 0.f;
            const unsigned short* rrow = routeB + (ntE*32 + l31)*264;
#pragma unroll 4
            for (int ks = 0; ks < 16; ks++) {
                int k0 = ks*16 + h*8;
                short8 bf = *(const short8*)(rrow + k0);
                short8 a0 = *(const short8*)(vcb + arowE + k0);
                cc = __builtin_amdgcn_mfma_f32_32x32x16_bf16(a0, bf, cc, 0, 0, 0);
            }
            int ng = w0 + ntE*32 + l31;
            if (ng < NWRD) {
                float* ob = out + (size_t)b*128*NWRD + ng;
#pragma unroll
                for (int i = 0; i < 16; i++) {
                    int crow = (i & 3) + 8*(i >> 2) + 4*h;
                    ob[(size_t)(ctE*32 + crow)*NWRD] = cc[i];
                }
            }
        }
        // no loop-top barrier: next fc1 writes h1b (not routeB); B1 guards fc2
    }
}

extern "C" void kernel_launch(void* const* d_in, const int* in_sizes, int n_in,
                              void* d_out, int out_size, void* d_ws, size_t ws_size,
                              hipStream_t stream) {
    const float* view_cell = (const float*)d_in[0];
    const float* v       = (const float*)d_in[1];
    const float* w2c_w1  = (const float*)d_in[2];
    const float* w2c_b1  = (const float*)d_in[3];
    const float* w2c_w2  = (const float*)d_in[4];
    const float* w2c_b2  = (const float*)d_in[5];
    const float* fc1_w   = (const float*)d_in[6];
    const float* fc1_b   = (const float*)d_in[7];
    const float* fc2_w   = (const float*)d_in[8];
    const float* fc2_b   = (const float*)d_in[9];
    const float* fca_w   = (const float*)d_in[10];
    const float* fca_b   = (const float*)d_in[11];
    const float* fce_w   = (const float*)d_in[12];
    const float* fce_b   = (const float*)d_in[13];
    const float* vse_w1  = (const float*)d_in[14];
    const float* vse_b1  = (const float*)d_in[15];
    const float* vse_w2  = (const float*)d_in[16];
    const float* vse_b2  = (const float*)d_in[17];
    float* ws    = (float*)d_ws;
    unsigned short* fc2wT = (unsigned short*)(ws + WS_FC2WT);
    float* wcode = ws + WS_WCODE;
    unsigned short* vsb   = (unsigned short*)(ws + WS_VSB);
    unsigned short* vcb   = (unsigned short*)(ws + WS_VCB);
    unsigned short* fcewT = (unsigned short*)(ws + WS_FCEWT);
    unsigned short* fcawB = (unsigned short*)(ws + WS_FCAWB);
    float* out   = (float*)d_out;

    kprep<<<PREP_N, 256, 0, stream>>>(view_cell, vcb,
                                      w2c_w2, v, w2c_w1, w2c_b1, w2c_b2, wcode,
                                      vse_w1, vse_b1, vse_w2, vse_b2, vsb,
                                      fc2_w, fc2wT, fce_w, fcewT, fca_w, fcawB);
    (void)hipFuncSetAttribute((const void*)k45,
                              hipFuncAttributeMaxDynamicSharedMemorySize, K45_LDS);
    dim3 g45(8, 64);
    k45<<<g45, 512, K45_LDS, stream>>>(vcb, wcode, fc1_w, fc1_b, fc2wT, fc2_b,
                                       fca_b, fcawB, fcewT, fce_b, vsb, out);
}